// Round 1
// baseline (1178.552 us; speedup 1.0000x reference)
//
#include <hip/hip_runtime.h>
#include <math.h>

#define HH 96
#define WW 96
#define NW 65            // window size (2*32+1)
#define NSRC 160         // noise row stride (H + 2D)
#define NT 256

#define OC 66            // Omega / Bt column stride
#define TC 34            // Tc/Ts/Rf column stride

__global__ __launch_bounds__(NT)
void fftma_kernel(const float* __restrict__ angle,
                  const float* __restrict__ noise,
                  float* __restrict__ out)
{
    __shared__ alignas(16) float Oc[NW][OC];   // cos twiddle matrix: Oc[i][j] = cos(2*pi*i*j/65)
    __shared__ alignas(16) float Os[NW][OC];   // sin twiddle matrix
    __shared__ alignas(16) float Bt[NW][OC];   // transposed data: RT[y][x] then WT[y][x]
    __shared__ alignas(16) float Tc[NW][TC];   // row-DFT cos part: [x][l]
    __shared__ alignas(16) float Ts[NW][TC];   // row-DFT sin part
    __shared__ alignas(16) float Rf[NW][TC];   // Rfideal[k][l] (real)
    __shared__ float tcs[66], tsn[66];
    __shared__ float red[4][4];

    const int tid = threadIdx.x;
    const int p   = blockIdx.x;
    const int py  = p / WW;
    const int px  = p - py * WW;

    // ---- twiddle tables (double-accurate args) ----
    if (tid < NW) {
        double a = 6.283185307179586 * (double)tid / 65.0;
        tcs[tid] = (float)cos(a);
        tsn[tid] = (float)sin(a);
    }
    __syncthreads();

    // ---- build Omega matrices + centered R kernel (transposed) ----
    const float theta = angle[p];
    const float cth = cosf(theta);
    const float sth = sinf(theta);

    for (int idx = tid; idx < NW * OC; idx += NT) {
        int i = idx / OC, j = idx - i * OC;
        float c = 0.f, s = 0.f;
        if (j < NW) { int m = (i * j) % NW; c = tcs[m]; s = tsn[m]; }
        Oc[i][j] = c; Os[i][j] = s;
    }
    for (int idx = tid; idx < NW * OC; idx += NT) {
        int y = idx / OC, x = idx - y * OC;
        float v = 0.f;
        if (x < NW) {
            float X = (float)(x <= 32 ? x : x - 65);
            float Y = (float)(y <= 32 ? y : y - 65);
            float u =  X * cth + Y * sth;
            float w = -X * sth + Y * cth;
            float q = (u * u) / 225.f + (w * w) / 9.f;
            v = expf(-sqrtf(q));
        }
        Bt[y][x] = v;   // RT[y][x] = Rideal[x][y]
    }
    __syncthreads();

    // tile coordinates (4x4 output tiles, 17 i-quads x 9 j-quads = 153 tasks)
    const int qi = tid / 9;
    const int qj = tid - qi * 9;
    const int i0 = qi * 4, j0 = qj * 4;
    const bool tileActive = (tid < 153);
    const bool iok = (i0 + 2 < NW);      // second b64 along i valid (i0 <= 60)
    const bool jok = (j0 + 2 < TC);      // second b64 along j valid (j0 <= 28)

    // ---- stage 3: row-DFT of R  -> Tc/Ts = TR[x][l] ----
    if (tileActive) {
        float aC[4][4], aS[4][4];
        #pragma unroll
        for (int i = 0; i < 4; i++)
            #pragma unroll
            for (int j = 0; j < 4; j++) { aC[i][j] = 0.f; aS[i][j] = 0.f; }

        for (int y = 0; y < NW; ++y) {
            float2 a01 = *(const float2*)&Bt[y][i0];
            float2 a23t = *(const float2*)&Bt[y][iok ? i0 + 2 : 0];
            float2 a23 = iok ? a23t : make_float2(0.f, 0.f);
            float2 c01 = *(const float2*)&Oc[y][j0];
            float2 c23 = *(const float2*)&Oc[y][j0 + 2];
            float2 s01 = *(const float2*)&Os[y][j0];
            float2 s23 = *(const float2*)&Os[y][j0 + 2];
            float av[4] = {a01.x, a01.y, a23.x, a23.y};
            float cv[4] = {c01.x, c01.y, c23.x, c23.y};
            float sv[4] = {s01.x, s01.y, s23.x, s23.y};
            #pragma unroll
            for (int i = 0; i < 4; i++)
                #pragma unroll
                for (int j = 0; j < 4; j++) {
                    aC[i][j] = fmaf(av[i], cv[j], aC[i][j]);
                    aS[i][j] = fmaf(av[i], sv[j], aS[i][j]);
                }
        }
        #pragma unroll
        for (int i = 0; i < 4; i++) {
            int x = i0 + i;
            if (x < NW) {
                #pragma unroll
                for (int j = 0; j < 4; j++) {
                    int l = j0 + j;
                    if (l < TC) { Tc[x][l] = aC[i][j]; Ts[x][l] = aS[i][j]; }
                }
            }
        }
    }
    __syncthreads();

    // ---- stage 4: col-DFT -> Rfideal[k][l] (real part only) ----
    if (tileActive) {
        float rA[4][4];
        #pragma unroll
        for (int i = 0; i < 4; i++)
            #pragma unroll
            for (int j = 0; j < 4; j++) rA[i][j] = 0.f;

        for (int x = 0; x < NW; ++x) {
            float2 oc01 = *(const float2*)&Oc[x][i0];
            float2 oc23t = *(const float2*)&Oc[x][iok ? i0 + 2 : 0];
            float2 os01 = *(const float2*)&Os[x][i0];
            float2 os23t = *(const float2*)&Os[x][iok ? i0 + 2 : 0];
            float2 oc23 = iok ? oc23t : make_float2(0.f, 0.f);
            float2 os23 = iok ? os23t : make_float2(0.f, 0.f);
            float2 bc01 = *(const float2*)&Tc[x][j0];
            float2 bc23t = *(const float2*)&Tc[x][jok ? j0 + 2 : 0];
            float2 bs01 = *(const float2*)&Ts[x][j0];
            float2 bs23t = *(const float2*)&Ts[x][jok ? j0 + 2 : 0];
            float2 bc23 = jok ? bc23t : make_float2(0.f, 0.f);
            float2 bs23 = jok ? bs23t : make_float2(0.f, 0.f);
            float ka[4] = {oc01.x, oc01.y, oc23.x, oc23.y};
            float sa[4] = {os01.x, os01.y, os23.x, os23.y};
            float cb[4] = {bc01.x, bc01.y, bc23.x, bc23.y};
            float sb[4] = {bs01.x, bs01.y, bs23.x, bs23.y};
            #pragma unroll
            for (int i = 0; i < 4; i++)
                #pragma unroll
                for (int j = 0; j < 4; j++) {
                    rA[i][j] = fmaf(ka[i], cb[j], rA[i][j]);
                    rA[i][j] = fmaf(-sa[i], sb[j], rA[i][j]);
                }
        }
        #pragma unroll
        for (int i = 0; i < 4; i++) {
            int k = i0 + i;
            if (k < NW) {
                #pragma unroll
                for (int j = 0; j < 4; j++) {
                    int l = j0 + j;
                    if (l < TC) Rf[k][l] = rA[i][j];
                }
            }
        }
    }

    // ---- stage 5a: load patch (transposed, zero pad col 65) into Bt ----
    for (int idx = tid; idx < OC * NW; idx += NT) {
        int x = idx / NW;            // 0..65
        int yy = idx - x * NW;       // 0..64
        float v = 0.f;
        if (x < NW) v = noise[(py + x) * NSRC + (px + yy)];
        Bt[yy][x] = v;
    }
    __syncthreads();

    // ---- stage 5b: row-DFT of patch -> Tc/Ts = TW[x][l] ----
    if (tileActive) {
        float aC[4][4], aS[4][4];
        #pragma unroll
        for (int i = 0; i < 4; i++)
            #pragma unroll
            for (int j = 0; j < 4; j++) { aC[i][j] = 0.f; aS[i][j] = 0.f; }

        for (int y = 0; y < NW; ++y) {
            float2 a01 = *(const float2*)&Bt[y][i0];
            float2 a23t = *(const float2*)&Bt[y][iok ? i0 + 2 : 0];
            float2 a23 = iok ? a23t : make_float2(0.f, 0.f);
            float2 c01 = *(const float2*)&Oc[y][j0];
            float2 c23 = *(const float2*)&Oc[y][j0 + 2];
            float2 s01 = *(const float2*)&Os[y][j0];
            float2 s23 = *(const float2*)&Os[y][j0 + 2];
            float av[4] = {a01.x, a01.y, a23.x, a23.y};
            float cv[4] = {c01.x, c01.y, c23.x, c23.y};
            float sv[4] = {s01.x, s01.y, s23.x, s23.y};
            #pragma unroll
            for (int i = 0; i < 4; i++)
                #pragma unroll
                for (int j = 0; j < 4; j++) {
                    aC[i][j] = fmaf(av[i], cv[j], aC[i][j]);
                    aS[i][j] = fmaf(av[i], sv[j], aS[i][j]);
                }
        }
        #pragma unroll
        for (int i = 0; i < 4; i++) {
            int x = i0 + i;
            if (x < NW) {
                #pragma unroll
                for (int j = 0; j < 4; j++) {
                    int l = j0 + j;
                    if (l < TC) { Tc[x][l] = aC[i][j]; Ts[x][l] = aS[i][j]; }
                }
            }
        }
    }
    __syncthreads();

    // ---- stage 6: col-DFT of patch (Wf) + pointwise spectral accumulation ----
    float accA = 0.f, accP = 0.f, accC = 0.f, accV = 0.f;
    if (tileActive) {
        float Wr[4][4], Wi[4][4];
        #pragma unroll
        for (int i = 0; i < 4; i++)
            #pragma unroll
            for (int j = 0; j < 4; j++) { Wr[i][j] = 0.f; Wi[i][j] = 0.f; }

        for (int x = 0; x < NW; ++x) {
            float2 oc01 = *(const float2*)&Oc[x][i0];
            float2 oc23t = *(const float2*)&Oc[x][iok ? i0 + 2 : 0];
            float2 os01 = *(const float2*)&Os[x][i0];
            float2 os23t = *(const float2*)&Os[x][iok ? i0 + 2 : 0];
            float2 oc23 = iok ? oc23t : make_float2(0.f, 0.f);
            float2 os23 = iok ? os23t : make_float2(0.f, 0.f);
            float2 bc01 = *(const float2*)&Tc[x][j0];
            float2 bc23t = *(const float2*)&Tc[x][jok ? j0 + 2 : 0];
            float2 bs01 = *(const float2*)&Ts[x][j0];
            float2 bs23t = *(const float2*)&Ts[x][jok ? j0 + 2 : 0];
            float2 bc23 = jok ? bc23t : make_float2(0.f, 0.f);
            float2 bs23 = jok ? bs23t : make_float2(0.f, 0.f);
            float ka[4] = {oc01.x, oc01.y, oc23.x, oc23.y};
            float sa[4] = {os01.x, os01.y, os23.x, os23.y};
            float cb[4] = {bc01.x, bc01.y, bc23.x, bc23.y};
            float sb[4] = {bs01.x, bs01.y, bs23.x, bs23.y};
            #pragma unroll
            for (int i = 0; i < 4; i++)
                #pragma unroll
                for (int j = 0; j < 4; j++) {
                    // Wf = sum (TWc - i*TWs)*(C - i*S)
                    Wr[i][j] = fmaf(cb[j], ka[i], Wr[i][j]);
                    Wr[i][j] = fmaf(-sb[j], sa[i], Wr[i][j]);
                    Wi[i][j] = fmaf(-cb[j], sa[i], Wi[i][j]);
                    Wi[i][j] = fmaf(-sb[j], ka[i], Wi[i][j]);
                }
        }

        #pragma unroll
        for (int i = 0; i < 4; i++) {
            #pragma unroll
            for (int j = 0; j < 4; j++) {
                int k = i0 + i, l = j0 + j;
                bool act = (k < NW) && (l < 33) && !((l == 0) && (k > 32));
                if (act) {
                    float wr = Wr[i][j], wi = Wi[i][j];
                    float rho = Rf[k][l];
                    int kl = k + l; if (kl >= 65) kl -= 65;
                    // Rf_shifted = rho * e^{+2pi i (k+l)/65}; z = Rf_shifted + 1e-8
                    float zr = fmaf(rho, tcs[kl], 1e-8f);
                    float zi = rho * tsn[kl];
                    float r  = sqrtf(zr * zr + zi * zi);
                    float Gr = sqrtf(fmaxf(0.5f * (r + zr), 0.f));
                    float Gm = sqrtf(fmaxf(0.5f * (r - zr), 0.f));
                    float Gi = (zi < 0.f) ? -Gm : Gm;        // principal csqrt
                    float Fr = wr * Gr - wi * Gi;
                    float Fi = wr * Gi + wi * Gr;
                    if (k == 0 && l == 0) {
                        accA += Fr * Fr + Fi * Fi;
                        accP += Fr * Fr - Fi * Fi;           // Re(F^2)
                        accC += Fr;                           // phase = 0
                        accV += Fr;                           // Re F[0,0]
                    } else {
                        // mirror bin (-k,-l): Wf_m = conj(Wf); G_m = conj-sqrt (same +i branch on cut)
                        float Gi2 = (zi == 0.f) ? Gi : -Gi;
                        float Fr2 = wr * Gr + wi * Gi2;
                        float Fi2 = wr * Gi2 - wi * Gr;
                        accA += Fr * Fr + Fi * Fi + Fr2 * Fr2 + Fi2 * Fi2;
                        accP += 2.f * (Fr * Fr2 - Fi * Fi2);
                        int m32 = (32 * (k + l)) % 65;
                        accC += Fr * tcs[m32] - Fi * tsn[m32]
                              + Fr2 * tcs[m32] + Fi2 * tsn[m32];
                    }
                }
            }
        }
    }

    // ---- block reduction ----
    #pragma unroll
    for (int off = 32; off > 0; off >>= 1) {
        accA += __shfl_down(accA, off);
        accP += __shfl_down(accP, off);
        accC += __shfl_down(accC, off);
        accV += __shfl_down(accV, off);
    }
    int wv = tid >> 6, ln = tid & 63;
    if (ln == 0) { red[wv][0] = accA; red[wv][1] = accP; red[wv][2] = accC; red[wv][3] = accV; }
    __syncthreads();
    if (tid == 0) {
        float A  = red[0][0] + red[1][0] + red[2][0] + red[3][0];
        float P  = red[0][1] + red[1][1] + red[2][1] + red[3][1];
        float Cs = red[0][2] + red[1][2] + red[2][2] + red[3][2];
        float V  = red[0][3] + red[1][3] + red[2][3] + red[3][3];
        const float Ntot = 4225.f;
        float mean = V / Ntot;
        float E2   = (P + A) * (0.5f / Ntot);        // sum of v^2
        float cen  = Cs / Ntot;                       // v[32,32]
        float var  = (E2 - Ntot * mean * mean) / (Ntot - 1.f);
        float sd   = sqrtf(fmaxf(var, 0.f));
        out[p] = (cen - mean) / (sd + 1e-6f);
    }
}

extern "C" void kernel_launch(void* const* d_in, const int* in_sizes, int n_in,
                              void* d_out, int out_size, void* d_ws, size_t ws_size,
                              hipStream_t stream)
{
    (void)in_sizes; (void)n_in; (void)out_size; (void)d_ws; (void)ws_size;
    const float* angle = (const float*)d_in[0];
    const float* noise = (const float*)d_in[1];
    float* outp = (float*)d_out;
    fftma_kernel<<<dim3(HH * WW), dim3(NT), 0, stream>>>(angle, noise, outp);
}